// Round 18
// baseline (25.319 us; speedup 1.0000x reference)
//
#include <hip/hip_runtime.h>
#include <hip/hip_bf16.h>
#include <stdint.h>

// out[n,f,i,j] = sum_k W[f,k]*patch[n,i,j,k] - 0.5||W_f||^2 - 0.5||X_{n,i,j}||^2
// x: (32,128,28,28) f32 ; W: (128,128,3,3) f32 ; out: (32,128,30,30) f32
// pad=2, ho=wo=30, L=28800, K=1152, F=128

#define N_IMG 32
#define C_IN 128
#define H_IN 28
#define HP 32
#define HO 30
#define P_SP 900
#define F_OUT 128
#define K_TOT 1152

#define BLT 60              // L-tile: 2 raster rows, no image crossing
#define TPI 15              // tiles per image
#define NBLK (N_IMG*TPI)    // 480 blocks x 512 threads; ~66KB LDS -> 2 blocks/CU
#define NSTEP 18            // K steps of BK=64

typedef __attribute__((ext_vector_type(8))) short bf16x8;
typedef __attribute__((ext_vector_type(4))) unsigned short u16x4;
typedef __attribute__((ext_vector_type(8))) unsigned short u16x8;
typedef __attribute__((ext_vector_type(16))) float f32x16;

__device__ __forceinline__ unsigned short f2bf(float f) {
  union { float f; unsigned u; } t; t.f = f;
  unsigned r = t.u + 0x7fffu + ((t.u >> 16) & 1u);
  return (unsigned short)(r >> 16);
}

// ---------------------------------------------------------------------------
// Kernel 1 (r16-verbatim): W -> Wfrag2 K-SLOT-MAJOR + wnorm.
// Wfrag2[ks=0..143][f=0..127][8 u16], ks = k'/8, k' = rr*128 + ch.
// ---------------------------------------------------------------------------
__global__ void prep_w_kernel(const float* __restrict__ W,
                              unsigned short* __restrict__ Wfrag2,
                              float* __restrict__ wnorm) {
  int f = blockIdx.x;
  const float* Wf = W + f * K_TOT;
  float part = 0.f;
  for (int k = threadIdx.x; k < K_TOT; k += 256) {
    float v = Wf[k];                 // k = ch*9 + rr
    part += v * v;
    int ch = k / 9, rr = k - ch * 9;
    int kp = rr * 128 + ch;          // k'
    Wfrag2[(kp >> 3) * 1024 + f * 8 + (kp & 7)] = f2bf(v);
  }
  __shared__ float red[256];
  red[threadIdx.x] = part;
  __syncthreads();
  for (int st = 128; st > 0; st >>= 1) {
    if (threadIdx.x < st) red[threadIdx.x] += red[threadIdx.x + st];
    __syncthreads();
  }
  if (threadIdx.x == 0) wnorm[f] = 0.5f * red[0];
}

// ---------------------------------------------------------------------------
// Kernel 2: r17 structure (32x32x16 MFMA, k-slot-major LDS), but the step's
// 4 MFMAs split across TWO accumulator chains (accA: c=0,2; accB: c=1,3;
// summed exactly in the epilogue). Restores the >=2-way MFMA ILP that made
// r16 fast while keeping 32x32's lower instruction count / pipe time.
// ---------------------------------------------------------------------------
__global__ __launch_bounds__(512, 4) void adder_fused_kernel(
    const float* __restrict__ x,
    const unsigned short* __restrict__ Wfrag2,
    const float* __restrict__ wnorm,
    float* __restrict__ out) {
  __shared__ unsigned short xfoot[128 * 130];   // first 32 KB slot layout; also Cst
  __shared__ unsigned short A_lds[2][64 * 128]; // 2 x 16 KB, [s4][row][8 u16]
  __shared__ float pixsum_s[128];
  __shared__ float xn_s[64];
  __shared__ float wn_s[F_OUT];

  int tid = threadIdx.x, lane = tid & 63, wid = tid >> 6;   // 8 waves
  int bid0 = blockIdx.x;
  int bid = (bid0 & 7) * (NBLK / 8) + (bid0 >> 3);   // XCD-chunked, bijective
  int n = bid / TPI, timg = bid - n * TPI;
  int i0 = timg * 2, p0 = timg * BLT;

  char* XF = (char*)xfoot;
  char* A0 = (char*)&A_lds[0][0];
  char* A1 = (char*)&A_lds[1][0];
  const char* WfB = (const char*)Wfrag2;

  // ---- A staging: chunk q = a*8 + wid; src byte == dst byte within tile ----
  int a_off[2];
#pragma unroll
  for (int a = 0; a < 2; a++) a_off[a] = (a * 8 + wid) * 1024 + lane * 16;

  auto STAGE = [&](int t, char* AB) {
    const char* src = WfB + t * 16384;
#pragma unroll
    for (int a = 0; a < 2; a++)
      __builtin_amdgcn_global_load_lds(
          (const __attribute__((address_space(1))) void*)(src + a_off[a]),
          (__attribute__((address_space(3))) void*)(AB + a_off[a]), 16, 0, 0);
  };

  // ---- prologue: wn load + A(0),A(1) DMA, then build xfoot2 ----
  if (tid < F_OUT) wn_s[tid] = wnorm[tid];
  STAGE(0, A0);
  STAGE(1, A1);

  // x conversion: u = cq*28 + r*7 + w4 (coalesced reads); write slot-major.
  for (int u = tid; u < 896; u += 512) {
    int cq = u / 28, rem = u - cq * 28;
    int r = rem / 7, w4 = rem - r * 7;
    int c = cq * 4;
    int hr = i0 - 2 + r;
    float vv[4][4];
    if (hr >= 0 && hr < H_IN) {
#pragma unroll
      for (int q = 0; q < 4; q++) {
        float4 t4 = *(const float4*)(x + (((n * C_IN + c + q) * H_IN + hr) * H_IN + w4 * 4));
        vv[q][0] = t4.x; vv[q][1] = t4.y; vv[q][2] = t4.z; vv[q][3] = t4.w;
      }
    } else {
#pragma unroll
      for (int q = 0; q < 4; q++)
#pragma unroll
        for (int e = 0; e < 4; e++) vv[q][e] = 0.f;
    }
#pragma unroll
    for (int e = 0; e < 4; e++) {
      int wp = w4 * 4 + e + 2;            // 2..29
      int pix = r * 32 + wp;
      u16x4 o;
#pragma unroll
      for (int q = 0; q < 4; q++) o[q] = f2bf(vv[q][e]);
      *(u16x4*)(XF + (c >> 3) * 2048 + pix * 16 + (c & 4) * 2) = o;
    }
  }
  // border zeros: wp in {0,1,30,31} x 4 rows x 16 slots (256 work items)
  if (tid < 256) {
    int r = tid >> 6, wi = (tid >> 4) & 3, slot = tid & 15;
    int wp = (wi < 2) ? wi : 28 + wi;     // 0,1,30,31
    int pix = r * 32 + wp;
    u16x8 z;
#pragma unroll
    for (int q = 0; q < 8; q++) z[q] = 0;
    *(u16x8*)(XF + slot * 2048 + pix * 16) = z;
  }
  __syncthreads();

  // per-pixel squared channel sums (2 threads per pixel; threads 0..255)
  if (tid < 256) {
    int pix = tid >> 1, ch = tid & 1;
    float ssum = 0.f;
#pragma unroll
    for (int q = 0; q < 8; q++) {
      u16x8 v8 = *(const u16x8*)(XF + (ch * 8 + q) * 2048 + pix * 16);
#pragma unroll
      for (int e = 0; e < 8; e++) {
        union { unsigned u; float f; } cv; cv.u = ((unsigned)v8[e]) << 16;
        ssum += cv.f * cv.f;
      }
    }
    ssum += __shfl_xor(ssum, 1);
    if (!ch) pixsum_s[pix] = ssum;
  }
  __syncthreads();
  if (tid < BLT) {
    int il = tid / HO, j = tid - il * HO;
    float a9 = 0.f;
#pragma unroll
    for (int dh = 0; dh < 3; dh++)
#pragma unroll
      for (int dw = 0; dw < 3; dw++)
        a9 += pixsum_s[(il + dh) * 32 + (j + dw)];
    xn_s[tid] = 0.5f * a9;
  }
  __syncthreads();   // full drain: A(0), A(1) landed; xfoot/xn_s visible

  // ---- K-loop: 32x32x16 MFMA, wave tile 32F x 32L, TWO acc chains ----
  f32x16 accA, accB;
#pragma unroll
  for (int r = 0; r < 16; r++) { accA[r] = 0.f; accB[r] = 0.f; }

  int wr = wid >> 1, wc = wid & 1;        // 4(F) x 2(L)
  int colb = lane & 31, kh = lane >> 5;   // row/col + k-half

  const char* Ab[2];                      // per-buffer A base
  {
    int rowf = wr * 32 + colb;
    Ab[0] = A0 + kh * 2048 + rowf * 16;
    Ab[1] = A1 + kh * 2048 + rowf * 16;
  }
  const char* Bb;                         // B base
  {
    int cc = wc * 32 + colb;
    if (cc > BLT - 1) cc = BLT - 1;       // dead cols: valid reads, dropped later
    int il = cc / HO, j = cc - il * HO;
    Bb = XF + kh * 2048 + (il * 32 + j) * 16;
  }

#pragma unroll
  for (int t = 0; t < NSTEP; t++) {
    const int buf = t & 1;
    const int rr = t >> 1, half = t & 1;
    const int dh = rr / 3, dw = rr - 3 * dh;
    const int bimm = half * 16384 + (dh * 32 + dw) * 16;   // compile-time
    bf16x8 af[4], bfv[4];
#pragma unroll
    for (int c = 0; c < 4; c++) {
      af[c] = *(const bf16x8*)(Ab[buf] + c * 4096);
      bfv[c] = *(const bf16x8*)(Bb + bimm + c * 4096);
    }
    __builtin_amdgcn_s_setprio(1);
    // two independent chains: A <- c0,c2 ; B <- c1,c3 (exact: summed at end)
    accA = __builtin_amdgcn_mfma_f32_32x32x16_bf16(af[0], bfv[0], accA, 0, 0, 0);
    accB = __builtin_amdgcn_mfma_f32_32x32x16_bf16(af[1], bfv[1], accB, 0, 0, 0);
    accA = __builtin_amdgcn_mfma_f32_32x32x16_bf16(af[2], bfv[2], accA, 0, 0, 0);
    accB = __builtin_amdgcn_mfma_f32_32x32x16_bf16(af[3], bfv[3], accB, 0, 0, 0);
    __builtin_amdgcn_s_setprio(0);

    __builtin_amdgcn_s_barrier();
    if (t + 2 < NSTEP) {
      STAGE(t + 2, buf ? A1 : A0);                        // refill just-freed buf
      asm volatile("s_waitcnt vmcnt(2)" ::: "memory");    // STAGE(t+1) landed
      __builtin_amdgcn_s_barrier();                       // t+2's 2 stay in flight
    } else if (t + 2 == NSTEP) {
      asm volatile("s_waitcnt vmcnt(0)" ::: "memory");    // tail: STAGE(17) landed
      __builtin_amdgcn_s_barrier();
    }
  }
  __syncthreads();   // step-17 xfoot B-reads done before Cst alias writes

  // ---- epilogue: acc = accA+accB -> Cst (stride 65) -> coalesced stores ----
  // C/D: col = lane&31, row = (r&3) + 8*(r>>2) + 4*(lane>>5)
  float* Cst = (float*)xfoot;             // [128][65] f32 = 33280 B exactly
  {
    int cc = wc * 32 + colb;
#pragma unroll
    for (int r = 0; r < 16; r++) {
      int rowl = (r & 3) + 8 * (r >> 2) + 4 * kh;
      Cst[(wr * 32 + rowl) * 65 + cc] = accA[r] + accB[r];
    }
  }
  __syncthreads();
  {
    int col = tid & 63, fq = tid >> 6;    // fq 0..7 -> 16 f each
    if (col < BLT) {
      float xn = xn_s[col];
      float* ob = out + (size_t)n * (F_OUT * P_SP) + p0 + col;
#pragma unroll
      for (int q = 0; q < 16; q++) {
        int f = fq * 16 + q;
        __builtin_nontemporal_store(Cst[f * 65 + col] - wn_s[f] - xn, ob + f * P_SP);
      }
    }
  }
}

// ---------------------------------------------------------------------------
extern "C" void kernel_launch(void* const* d_in, const int* in_sizes, int n_in,
                              void* d_out, int out_size, void* d_ws, size_t ws_size,
                              hipStream_t stream) {
  const float* x = (const float*)d_in[0];
  const float* W = (const float*)d_in[1];
  float* out = (float*)d_out;

  char* ws = (char*)d_ws;
  unsigned short* Wfrag2 = (unsigned short*)(ws);    // 294,912 B
  float* wnorm = (float*)(ws + 294912);              //     512 B

  prep_w_kernel<<<F_OUT, 256, 0, stream>>>(W, Wfrag2, wnorm);
  adder_fused_kernel<<<NBLK, 512, 0, stream>>>(x, Wfrag2, wnorm, out);
}

// Round 19
// 24.780 us; speedup vs baseline: 1.0218x; 1.0218x over previous
//
#include <hip/hip_runtime.h>
#include <hip/hip_bf16.h>
#include <stdint.h>

// out[n,f,i,j] = sum_k W[f,k]*patch[n,i,j,k] - 0.5||W_f||^2 - 0.5||X_{n,i,j}||^2
// x: (32,128,28,28) f32 ; W: (128,128,3,3) f32 ; out: (32,128,30,30) f32
// pad=2, ho=wo=30, L=28800, K=1152, F=128
//
// FINAL (r16-verbatim, measured best: 24.8 us):
//  - k-slot-major layouts (zero-VALU, swizzle-free, conflict-free LDS reads)
//  - fused x-prep in LDS (im2col reuse never touches global)
//  - counted-vmcnt double-buffered A stream via global_load_lds
//  - 512 threads (4 waves/SIMD), XCD-chunked block remap
//  - 16x16x32 MFMA, 4 independent accumulator chains
//  - Cst-transpose epilogue with fused norm subtraction

#define N_IMG 32
#define C_IN 128
#define H_IN 28
#define HP 32
#define HO 30
#define P_SP 900
#define F_OUT 128
#define K_TOT 1152

#define BLT 60              // L-tile: 2 raster rows, no image crossing
#define TPI 15              // tiles per image
#define NBLK (N_IMG*TPI)    // 480 blocks x 512 threads; ~66KB LDS -> 2 blocks/CU
#define NSTEP 18            // K steps of BK=64

typedef __attribute__((ext_vector_type(8))) short bf16x8;
typedef __attribute__((ext_vector_type(4))) unsigned short u16x4;
typedef __attribute__((ext_vector_type(8))) unsigned short u16x8;
typedef __attribute__((ext_vector_type(4))) float f32x4;

__device__ __forceinline__ unsigned short f2bf(float f) {
  union { float f; unsigned u; } t; t.f = f;
  unsigned r = t.u + 0x7fffu + ((t.u >> 16) & 1u);
  return (unsigned short)(r >> 16);
}

// ---------------------------------------------------------------------------
// Kernel 1: W -> Wfrag2 K-SLOT-MAJOR layout + wnorm.
// Wfrag2[ks=0..143][f=0..127][8 u16]: ks = k'/8, k' = rr*128 + ch.
// K-step tile t (BK=64) = bytes [t*16384, +16384): 16 contiguous 1-KB chunks
// -> STAGE source == dest == q*1024 + lane*16 (fully coalesced).
// ---------------------------------------------------------------------------
__global__ void prep_w_kernel(const float* __restrict__ W,
                              unsigned short* __restrict__ Wfrag2,
                              float* __restrict__ wnorm) {
  int f = blockIdx.x;
  const float* Wf = W + f * K_TOT;
  float part = 0.f;
  for (int k = threadIdx.x; k < K_TOT; k += 256) {
    float v = Wf[k];                 // k = ch*9 + rr
    part += v * v;
    int ch = k / 9, rr = k - ch * 9;
    int kp = rr * 128 + ch;          // k'
    Wfrag2[(kp >> 3) * 1024 + f * 8 + (kp & 7)] = f2bf(v);
  }
  __shared__ float red[256];
  red[threadIdx.x] = part;
  __syncthreads();
  for (int st = 128; st > 0; st >>= 1) {
    if (threadIdx.x < st) red[threadIdx.x] += red[threadIdx.x + st];
    __syncthreads();
  }
  if (threadIdx.x == 0) wnorm[f] = 0.5f * red[0];
}

// ---------------------------------------------------------------------------
// Kernel 2: fused x-prep + implicit-im2col GEMM, k-slot-major LDS layouts.
//  - xfoot2[s=0..15][pix=0..127][16B] (32 KB): fragment read = per-lane base
//    (kg*2048 + pix0*16) + COMPILE-TIME immediate (half*16384 + kc*8192 +
//    pofs*16). No swizzle, no XOR, 2-way banks (free).
//  - A_lds[2][s4=0..7][row=0..127][16B]: read = per-lane base + kc*8192 imm.
//  - STAGE: src/dst both q*1024 + lane*16 (1-KB contiguous chunks).
//  - Full 18-step unroll; counted vmcnt(2); 2 barriers/step; setprio;
//    XCD-chunked remap; 512 threads (4 waves/SIMD).
// ---------------------------------------------------------------------------
__global__ __launch_bounds__(512, 4) void adder_fused_kernel(
    const float* __restrict__ x,
    const unsigned short* __restrict__ Wfrag2,
    const float* __restrict__ wnorm,
    float* __restrict__ out) {
  __shared__ unsigned short xfoot[128 * 130];   // first 32 KB = slot layout; also Cst
  __shared__ unsigned short A_lds[2][64 * 128]; // 2 x 16 KB, [s4][row][8 u16]
  __shared__ float pixsum_s[128];
  __shared__ float xn_s[64];
  __shared__ float wn_s[F_OUT];

  int tid = threadIdx.x, lane = tid & 63, wid = tid >> 6;   // 8 waves
  int bid0 = blockIdx.x;
  int bid = (bid0 & 7) * (NBLK / 8) + (bid0 >> 3);   // XCD-chunked, bijective
  int n = bid / TPI, timg = bid - n * TPI;
  int i0 = timg * 2, p0 = timg * BLT;

  char* XF = (char*)xfoot;
  char* A0 = (char*)&A_lds[0][0];
  char* A1 = (char*)&A_lds[1][0];
  const char* WfB = (const char*)Wfrag2;

  // ---- A staging: chunk q = a*8 + wid; src byte == dst byte within tile ----
  int a_off[2];
#pragma unroll
  for (int a = 0; a < 2; a++) a_off[a] = (a * 8 + wid) * 1024 + lane * 16;

  auto STAGE = [&](int t, char* AB) {
    const char* src = WfB + t * 16384;
#pragma unroll
    for (int a = 0; a < 2; a++)
      __builtin_amdgcn_global_load_lds(
          (const __attribute__((address_space(1))) void*)(src + a_off[a]),
          (__attribute__((address_space(3))) void*)(AB + a_off[a]), 16, 0, 0);
  };

  // ---- prologue: wn load + A(0),A(1) DMA, then build xfoot2 ----
  if (tid < F_OUT) wn_s[tid] = wnorm[tid];
  STAGE(0, A0);
  STAGE(1, A1);

  // x conversion: u = cq*28 + r*7 + w4 (coalesced reads); write slot-major.
  for (int u = tid; u < 896; u += 512) {
    int cq = u / 28, rem = u - cq * 28;
    int r = rem / 7, w4 = rem - r * 7;
    int c = cq * 4;
    int hr = i0 - 2 + r;
    float vv[4][4];
    if (hr >= 0 && hr < H_IN) {
#pragma unroll
      for (int q = 0; q < 4; q++) {
        float4 t4 = *(const float4*)(x + (((n * C_IN + c + q) * H_IN + hr) * H_IN + w4 * 4));
        vv[q][0] = t4.x; vv[q][1] = t4.y; vv[q][2] = t4.z; vv[q][3] = t4.w;
      }
    } else {
#pragma unroll
      for (int q = 0; q < 4; q++)
#pragma unroll
        for (int e = 0; e < 4; e++) vv[q][e] = 0.f;
    }
#pragma unroll
    for (int e = 0; e < 4; e++) {
      int wp = w4 * 4 + e + 2;            // 2..29
      int pix = r * 32 + wp;
      u16x4 o;
#pragma unroll
      for (int q = 0; q < 4; q++) o[q] = f2bf(vv[q][e]);
      // slot s = c>>3, in-entry byte = (c&4)*2
      *(u16x4*)(XF + (c >> 3) * 2048 + pix * 16 + (c & 4) * 2) = o;
    }
  }
  // border zeros: wp in {0,1,30,31} x 4 rows x 16 slots (256 work items)
  if (tid < 256) {
    int r = tid >> 6, wi = (tid >> 4) & 3, slot = tid & 15;
    int wp = (wi < 2) ? wi : 28 + wi;     // 0,1,30,31
    int pix = r * 32 + wp;
    u16x8 z;
#pragma unroll
    for (int q = 0; q < 8; q++) z[q] = 0;
    *(u16x8*)(XF + slot * 2048 + pix * 16) = z;
  }
  __syncthreads();

  // per-pixel squared channel sums (2 threads per pixel; threads 0..255)
  if (tid < 256) {
    int pix = tid >> 1, ch = tid & 1;
    float ssum = 0.f;
#pragma unroll
    for (int q = 0; q < 8; q++) {
      u16x8 v8 = *(const u16x8*)(XF + (ch * 8 + q) * 2048 + pix * 16);
#pragma unroll
      for (int e = 0; e < 8; e++) {
        union { unsigned u; float f; } cv; cv.u = ((unsigned)v8[e]) << 16;
        ssum += cv.f * cv.f;
      }
    }
    ssum += __shfl_xor(ssum, 1);
    if (!ch) pixsum_s[pix] = ssum;
  }
  __syncthreads();
  if (tid < BLT) {
    int il = tid / HO, j = tid - il * HO;
    float a9 = 0.f;
#pragma unroll
    for (int dh = 0; dh < 3; dh++)
#pragma unroll
      for (int dw = 0; dw < 3; dw++)
        a9 += pixsum_s[(il + dh) * 32 + (j + dw)];
    xn_s[tid] = 0.5f * a9;
  }
  __syncthreads();   // full drain: A(0), A(1) landed; xfoot/xn_s visible

  // ---- K-loop: wave tile 32F x 32L; zero-VALU fragment addressing ----
  f32x4 acc[2][2];
#pragma unroll
  for (int mi = 0; mi < 2; mi++)
#pragma unroll
    for (int ni = 0; ni < 2; ni++)
      acc[mi][ni] = (f32x4){0.f, 0.f, 0.f, 0.f};

  int wr = wid >> 1, wc = wid & 1;        // 4(F) x 2(L)
  int colc = lane & 15, kg = lane >> 4;

  // per-lane bases (computed once)
  const char* Ab[2][2];                   // [buffer][mi]
#pragma unroll
  for (int mi = 0; mi < 2; mi++) {
    int rowf = wr * 32 + mi * 16 + colc;
    Ab[0][mi] = A0 + kg * 2048 + rowf * 16;
    Ab[1][mi] = A1 + kg * 2048 + rowf * 16;
  }
  const char* Bb[2];                      // [ni]
#pragma unroll
  for (int ni = 0; ni < 2; ni++) {
    int cc = wc * 32 + ni * 16 + colc;
    if (cc > BLT - 1) cc = BLT - 1;       // dead cols: valid reads, dropped later
    int il = cc / HO, j = cc - il * HO;
    Bb[ni] = XF + kg * 2048 + (il * 32 + j) * 16;
  }

#pragma unroll
  for (int t = 0; t < NSTEP; t++) {
    const int buf = t & 1;
    const int rr = t >> 1, half = t & 1;
    const int dh = rr / 3, dw = rr - 3 * dh;
    const int bimm = half * 16384 + (dh * 32 + dw) * 16;   // compile-time
#pragma unroll
    for (int kc = 0; kc < 2; kc++) {
      bf16x8 af[2], bfv[2];
#pragma unroll
      for (int mi = 0; mi < 2; mi++)
        af[mi] = *(const bf16x8*)(Ab[buf][mi] + kc * 8192);
#pragma unroll
      for (int ni = 0; ni < 2; ni++)
        bfv[ni] = *(const bf16x8*)(Bb[ni] + bimm + kc * 8192);
      __builtin_amdgcn_s_setprio(1);
#pragma unroll
      for (int mi = 0; mi < 2; mi++)
#pragma unroll
        for (int ni = 0; ni < 2; ni++)
          acc[mi][ni] = __builtin_amdgcn_mfma_f32_16x16x32_bf16(
              af[mi], bfv[ni], acc[mi][ni], 0, 0, 0);
      __builtin_amdgcn_s_setprio(0);
    }
    __builtin_amdgcn_s_barrier();
    if (t + 2 < NSTEP) {
      STAGE(t + 2, buf ? A1 : A0);                        // refill just-freed buf
      asm volatile("s_waitcnt vmcnt(2)" ::: "memory");    // STAGE(t+1) landed
      __builtin_amdgcn_s_barrier();                       // t+2's 2 stay in flight
    } else if (t + 2 == NSTEP) {
      asm volatile("s_waitcnt vmcnt(0)" ::: "memory");    // tail: STAGE(17) landed
      __builtin_amdgcn_s_barrier();
    }
  }
  __syncthreads();   // step-17 xfoot B-reads done before Cst alias writes

  // ---- epilogue: acc -> Cst (stride 65, aliases xfoot) -> coalesced stores ----
  float* Cst = (float*)xfoot;             // [128][65] f32 = 33280 B exactly
  int kg4 = kg * 4;
#pragma unroll
  for (int mi = 0; mi < 2; mi++) {
    int f0 = wr * 32 + mi * 16 + kg4;
#pragma unroll
    for (int ni = 0; ni < 2; ni++) {
      int cc = wc * 32 + ni * 16 + colc;
#pragma unroll
      for (int r = 0; r < 4; r++)
        Cst[(f0 + r) * 65 + cc] = acc[mi][ni][r];
    }
  }
  __syncthreads();
  {
    int col = tid & 63, fq = tid >> 6;    // fq 0..7 -> 16 f each
    if (col < BLT) {
      float xn = xn_s[col];
      float* ob = out + (size_t)n * (F_OUT * P_SP) + p0 + col;
#pragma unroll
      for (int q = 0; q < 16; q++) {
        int f = fq * 16 + q;
        __builtin_nontemporal_store(Cst[f * 65 + col] - wn_s[f] - xn, ob + f * P_SP);
      }
    }
  }
}

// ---------------------------------------------------------------------------
extern "C" void kernel_launch(void* const* d_in, const int* in_sizes, int n_in,
                              void* d_out, int out_size, void* d_ws, size_t ws_size,
                              hipStream_t stream) {
  const float* x = (const float*)d_in[0];
  const float* W = (const float*)d_in[1];
  float* out = (float*)d_out;

  char* ws = (char*)d_ws;
  unsigned short* Wfrag2 = (unsigned short*)(ws);    // 294,912 B
  float* wnorm = (float*)(ws + 294912);              //     512 B

  prep_w_kernel<<<F_OUT, 256, 0, stream>>>(W, Wfrag2, wnorm);
  adder_fused_kernel<<<NBLK, 512, 0, stream>>>(x, Wfrag2, wnorm, out);
}